// Round 2
// baseline (478.442 us; speedup 1.0000x reference)
//
#include <hip/hip_runtime.h>

typedef short bf16x8 __attribute__((ext_vector_type(8)));
typedef float f32x4 __attribute__((ext_vector_type(4)));

__device__ __forceinline__ ushort f2bf(float f) {
    union { float f; unsigned u; } v; v.f = f;
    unsigned r = (v.u + 0x7fffu + ((v.u >> 16) & 1u)) >> 16;
    return (ushort)r;
}
__device__ __forceinline__ float bf2f(ushort u) {
    union { unsigned u; float f; } v; v.u = ((unsigned)u) << 16;
    return v.f;
}

// ---------------- fp32 -> bf16 conversion ----------------
__global__ __launch_bounds__(256)
void cvt_f32_bf16(const float* __restrict__ src, ushort* __restrict__ dst, int n) {
    int i = (blockIdx.x * 256 + threadIdx.x) * 4;
    if (i >= n) return;
    float4 v = *(const float4*)(src + i);
    ushort4 o;
    o.x = f2bf(v.x); o.y = f2bf(v.y); o.z = f2bf(v.z); o.w = f2bf(v.w);
    *(ushort4*)(dst + i) = o;
}

// ---------------- C[m][n] = sum_k A[m][k] * B[n][k], bf16 in/out, fp32 acc ----
__global__ __launch_bounds__(256, 2)
void gemm_bt(const ushort* __restrict__ A, const ushort* __restrict__ B,
             ushort* __restrict__ C, int M, int N, int K)
{
    __shared__ ushort As[128][40];
    __shared__ ushort Bs[128][40];
    const int tid = threadIdx.x;
    const int lane = tid & 63, wave = tid >> 6;
    const int wm = wave >> 1, wn = wave & 1;
    const int lr = lane & 15, lq = lane >> 4;
    const int mBase = blockIdx.y * 128, nBase = blockIdx.x * 128;

    f32x4 acc[4][4];
    #pragma unroll
    for (int i = 0; i < 4; ++i)
        #pragma unroll
        for (int j = 0; j < 4; ++j) acc[i][j] = (f32x4){0.f, 0.f, 0.f, 0.f};

    for (int k0 = 0; k0 < K; k0 += 32) {
        __syncthreads();
        #pragma unroll
        for (int i = 0; i < 2; ++i) {
            int off = i * 4096 + tid * 16;
            int row = off >> 6, col = off & 63;
            *(uint4*)((char*)As + row * 80 + col) =
                *(const uint4*)((const char*)A + ((size_t)(mBase + row) * K + k0) * 2 + col);
            *(uint4*)((char*)Bs + row * 80 + col) =
                *(const uint4*)((const char*)B + ((size_t)(nBase + row) * K + k0) * 2 + col);
        }
        __syncthreads();
        bf16x8 af[4], bfr[4];
        #pragma unroll
        for (int mi = 0; mi < 4; ++mi) af[mi] = *(const bf16x8*)&As[wm * 64 + mi * 16 + lr][lq * 8];
        #pragma unroll
        for (int ni = 0; ni < 4; ++ni) bfr[ni] = *(const bf16x8*)&Bs[wn * 64 + ni * 16 + lr][lq * 8];
        #pragma unroll
        for (int mi = 0; mi < 4; ++mi)
            #pragma unroll
            for (int ni = 0; ni < 4; ++ni)
                acc[mi][ni] = __builtin_amdgcn_mfma_f32_16x16x32_bf16(af[mi], bfr[ni], acc[mi][ni], 0, 0, 0);
    }
    #pragma unroll
    for (int mi = 0; mi < 4; ++mi)
        #pragma unroll
        for (int ni = 0; ni < 4; ++ni)
            #pragma unroll
            for (int r = 0; r < 4; ++r) {
                int m = mBase + wm * 64 + mi * 16 + lq * 4 + r;
                int n = nBase + wn * 64 + ni * 16 + lr;
                C[(size_t)m * N + n] = f2bf(acc[mi][ni][r]);
            }
}

// ---------------- flash attention, split-S ----------------
// Q,K: [B*S, 512] bf16 row-major. Vt: [512, B*S] bf16 (row stride 16384).
// Grid (32, 8, 2): 64 Q-rows per block; blockIdx.z = which half of the keys
// (1024 each). Writes UNNORMALIZED partial O (bf16) + per-row (m, l).
__global__ __launch_bounds__(256, 2)
void attn_kernel(const ushort* __restrict__ Qg, const ushort* __restrict__ Kg,
                 const ushort* __restrict__ Vtg, const int* __restrict__ maskg,
                 ushort* __restrict__ Pog, float2* __restrict__ Mlg)
{
    const int S = 2048, D = 512;
    const float SL2E = 0.0637587160f;  // (1/sqrt(512)) * log2(e)

    __shared__ ushort Ks[32][520];   // 32 keys x 512 d (+8 pad)   33280 B
    __shared__ ushort Vs[512][40];   // 512 d   x 32 keys (+8 pad) 40960 B
    __shared__ ushort Ps[4][16][40]; // per-wave P 16x32 (+8 pad)   5120 B

    const int b = blockIdx.y, qt = blockIdx.x, half = blockIdx.z;
    const int tid = threadIdx.x, lane = tid & 63, wave = tid >> 6;
    const int lr = lane & 15, lq = lane >> 4;

    const ushort* Qp = Qg + ((size_t)b * S + qt * 64 + wave * 16 + lr) * D;
    bf16x8 qf[16];
    #pragma unroll
    for (int c = 0; c < 16; ++c) qf[c] = *(const bf16x8*)(Qp + c * 32 + lq * 8);

    f32x4 o[32];
    #pragma unroll
    for (int i = 0; i < 32; ++i) o[i] = (f32x4){0.f, 0.f, 0.f, 0.f};
    float m_i[4] = {-1e30f, -1e30f, -1e30f, -1e30f};
    float l_i[4] = {0.f, 0.f, 0.f, 0.f};

    const char* Kbase = (const char*)(Kg + (size_t)b * S * D);
    const char* Vbase = (const char*)Vtg + (size_t)b * 4096;
    const int* mrow = maskg + b * S + half * 1024;
    const char* Khalf = Kbase + (size_t)half * 1024 * 1024;
    const char* Vhalf = Vbase + (size_t)half * 2048;

    for (int kt = 0; kt < 32; ++kt) {
        const int key0 = kt * 32;
        __syncthreads();
        {   // stage K tile: 32 keys x 1024 B
            const char* gK = Khalf + (size_t)key0 * 1024;
            #pragma unroll
            for (int i = 0; i < 8; ++i) {
                int off = i * 4096 + tid * 16;
                int row = off >> 10, col = off & 1023;
                *(uint4*)((char*)Ks + row * 1040 + col) =
                    *(const uint4*)(gK + (size_t)row * 1024 + col);
            }
            // stage V tile: 512 d-rows x 64 B
            const char* gV = Vhalf + (size_t)key0 * 2;
            #pragma unroll
            for (int i = 0; i < 8; ++i) {
                int off = i * 4096 + tid * 16;
                int row = off >> 6, col = off & 63;
                *(uint4*)((char*)Vs + row * 80 + col) =
                    *(const uint4*)(gV + (size_t)row * 32768 + col);
            }
        }
        __syncthreads();
        // S = Q Ktile^T
        f32x4 sf0 = (f32x4){0.f,0.f,0.f,0.f}, sf1 = (f32x4){0.f,0.f,0.f,0.f};
        #pragma unroll
        for (int ks = 0; ks < 16; ++ks) {
            bf16x8 kf0 = *(const bf16x8*)&Ks[lr][ks * 32 + lq * 8];
            bf16x8 kf1 = *(const bf16x8*)&Ks[16 + lr][ks * 32 + lq * 8];
            sf0 = __builtin_amdgcn_mfma_f32_16x16x32_bf16(qf[ks], kf0, sf0, 0, 0, 0);
            sf1 = __builtin_amdgcn_mfma_f32_16x16x32_bf16(qf[ks], kf1, sf1, 0, 0, 0);
        }
        // online softmax (log2 domain). C-layout: col(key)=lane&15, row=lq*4+r.
        const bool msk0 = mrow[key0 + lr] != 0;
        const bool msk1 = mrow[key0 + 16 + lr] != 0;
        float t0[4], t1[4], rmax[4];
        #pragma unroll
        for (int r = 0; r < 4; ++r) {
            t0[r] = msk0 ? -1e30f : sf0[r] * SL2E;
            t1[r] = msk1 ? -1e30f : sf1[r] * SL2E;
            rmax[r] = fmaxf(t0[r], t1[r]);
        }
        #pragma unroll
        for (int r = 0; r < 4; ++r)
            #pragma unroll
            for (int off = 1; off < 16; off <<= 1)
                rmax[r] = fmaxf(rmax[r], __shfl_xor(rmax[r], off, 16));
        float alpha[4], p0[4], p1[4], psum[4];
        #pragma unroll
        for (int r = 0; r < 4; ++r) {
            float mn = fmaxf(m_i[r], rmax[r]);
            alpha[r] = exp2f(m_i[r] - mn);
            m_i[r] = mn;
            p0[r] = exp2f(t0[r] - mn);
            p1[r] = exp2f(t1[r] - mn);
            psum[r] = p0[r] + p1[r];
        }
        #pragma unroll
        for (int r = 0; r < 4; ++r) {
            #pragma unroll
            for (int off = 1; off < 16; off <<= 1)
                psum[r] += __shfl_xor(psum[r], off, 16);
            l_i[r] = l_i[r] * alpha[r] + psum[r];
        }
        // P: C-layout -> LDS -> A-layout (wave-private buffer)
        #pragma unroll
        for (int r = 0; r < 4; ++r) {
            Ps[wave][lq * 4 + r][lr]      = f2bf(p0[r]);
            Ps[wave][lq * 4 + r][16 + lr] = f2bf(p1[r]);
        }
        // rescale O only if any alpha < 1 (wave-uniform skip)
        bool needscale = (alpha[0] < 1.f) | (alpha[1] < 1.f) |
                         (alpha[2] < 1.f) | (alpha[3] < 1.f);
        if (__any(needscale)) {
            #pragma unroll
            for (int i = 0; i < 32; ++i) {
                o[i][0] *= alpha[0]; o[i][1] *= alpha[1];
                o[i][2] *= alpha[2]; o[i][3] *= alpha[3];
            }
        }
        bf16x8 pf = *(const bf16x8*)&Ps[wave][lr][lq * 8];
        // O += P @ Vt-tile (all 512 d)
        #pragma unroll
        for (int db = 0; db < 32; ++db) {
            bf16x8 vf = *(const bf16x8*)&Vs[db * 16 + lr][lq * 8];
            o[db] = __builtin_amdgcn_mfma_f32_16x16x32_bf16(pf, vf, o[db], 0, 0, 0);
        }
    }
    // write unnormalized partial O (bf16) + (m,l) per row
    const size_t growbase = (size_t)half * 16384 + (size_t)b * S + qt * 64 + wave * 16;
    ushort* Pop = Pog + (growbase + lq * 4) * D;
    #pragma unroll
    for (int db = 0; db < 32; ++db)
        #pragma unroll
        for (int r = 0; r < 4; ++r)
            Pop[(size_t)r * D + db * 16 + lr] = f2bf(o[db][r]);
    if (lr == 0) {
        #pragma unroll
        for (int r = 0; r < 4; ++r)
            Mlg[growbase + lq * 4 + r] = make_float2(m_i[r], l_i[r]);
    }
}

// ---------------- combine the two key-halves ----------------
__global__ __launch_bounds__(256)
void combine_kernel(const ushort* __restrict__ Po, const float2* __restrict__ Ml,
                    float* __restrict__ out)
{
    int i = (blockIdx.x * 256 + threadIdx.x) * 4;   // element index into 16384x512
    int row = i >> 9;
    float2 a = Ml[row], c = Ml[16384 + row];
    float m = fmaxf(a.x, c.x);
    float w1 = exp2f(a.x - m), w2 = exp2f(c.x - m);
    float denom = a.y * w1 + c.y * w2;
    float s = denom > 0.f ? 1.f / denom : 0.f;
    float s1 = w1 * s, s2 = w2 * s;
    ushort4 p1 = *(const ushort4*)(Po + i);
    ushort4 p2 = *(const ushort4*)(Po + 8388608 + i);
    float4 o;
    o.x = bf2f(p1.x) * s1 + bf2f(p2.x) * s2;
    o.y = bf2f(p1.y) * s1 + bf2f(p2.y) * s2;
    o.z = bf2f(p1.z) * s1 + bf2f(p2.z) * s2;
    o.w = bf2f(p1.w) * s1 + bf2f(p2.w) * s2;
    *(float4*)(out + i) = o;
}

extern "C" void kernel_launch(void* const* d_in, const int* in_sizes, int n_in,
                              void* d_out, int out_size, void* d_ws, size_t ws_size,
                              hipStream_t stream) {
    const float* x  = (const float*)d_in[0];
    // d_in[1] = bias: additive scalar on all logits -> softmax shift-invariant -> no-op
    const int* mask = (const int*)d_in[2];
    const float* Wq = (const float*)d_in[3];
    const float* Wk = (const float*)d_in[4];
    const float* Wv = (const float*)d_in[5];
    float* out = (float*)d_out;

    // Workspace (ushort units). Region [0, 16777216) is time-shared:
    //   phase 1 (cvt+gemm): xb (8388608) + wq/wk/wv (3x262144)
    //   phase 2 (attn+combine): Po (2x8388608 bf16 partial O)
    ushort* ws  = (ushort*)d_ws;
    ushort* xb  = ws;
    ushort* wqb = ws + 8388608;
    ushort* wkb = wqb + 262144;
    ushort* wvb = wkb + 262144;
    ushort* Pob = ws;                 // overlaps xb+w (dead after gemms)
    ushort* Qb  = ws + 16777216;
    ushort* Kb  = Qb + 8388608;
    ushort* Vtb = Kb + 8388608;
    float2* Mlb = (float2*)(Vtb + 8388608);  // 32768 float2

    cvt_f32_bf16<<<8192, 256, 0, stream>>>(x, xb, 8388608);
    cvt_f32_bf16<<<256, 256, 0, stream>>>(Wq, wqb, 262144);
    cvt_f32_bf16<<<256, 256, 0, stream>>>(Wk, wkb, 262144);
    cvt_f32_bf16<<<256, 256, 0, stream>>>(Wv, wvb, 262144);
    gemm_bt<<<dim3(4, 128), 256, 0, stream>>>(xb, wqb, Qb, 16384, 512, 512);
    gemm_bt<<<dim3(4, 128), 256, 0, stream>>>(xb, wkb, Kb, 16384, 512, 512);
    gemm_bt<<<dim3(128, 4), 256, 0, stream>>>(wvb, xb, Vtb, 512, 16384, 512);
    attn_kernel<<<dim3(32, 8, 2), 256, 0, stream>>>(Qb, Kb, Vtb, mask, Pob, Mlb);
    combine_kernel<<<8192, 256, 0, stream>>>(Pob, Mlb, out);
}

// Round 3
// 309.157 us; speedup vs baseline: 1.5476x; 1.5476x over previous
//
#include <hip/hip_runtime.h>

typedef short bf16x8 __attribute__((ext_vector_type(8)));
typedef float f32x4 __attribute__((ext_vector_type(4)));

__device__ __forceinline__ ushort f2bf(float f) {
    union { float f; unsigned u; } v; v.f = f;
    unsigned r = (v.u + 0x7fffu + ((v.u >> 16) & 1u)) >> 16;
    return (ushort)r;
}
__device__ __forceinline__ float bf2f(ushort u) {
    union { unsigned u; float f; } v; v.u = ((unsigned)u) << 16;
    return v.f;
}
__device__ __forceinline__ void async_copy16(void* lds, const void* g) {
    __builtin_amdgcn_global_load_lds(
        (const __attribute__((address_space(1))) unsigned*)g,
        (__attribute__((address_space(3))) unsigned*)lds, 16, 0, 0);
}

// ---------------- fp32 -> bf16 conversion ----------------
__global__ __launch_bounds__(256)
void cvt_f32_bf16(const float* __restrict__ src, ushort* __restrict__ dst, int n) {
    int i = (blockIdx.x * 256 + threadIdx.x) * 4;
    if (i >= n) return;
    float4 v = *(const float4*)(src + i);
    ushort4 o;
    o.x = f2bf(v.x); o.y = f2bf(v.y); o.z = f2bf(v.z); o.w = f2bf(v.w);
    *(ushort4*)(dst + i) = o;
}

// ---------------- C[m][n] = sum_k A[m][k] * B[n][k], bf16 in/out, fp32 acc ----
__global__ __launch_bounds__(256, 2)
void gemm_bt(const ushort* __restrict__ A, const ushort* __restrict__ B,
             ushort* __restrict__ C, int M, int N, int K)
{
    __shared__ ushort As[128][40];
    __shared__ ushort Bs[128][40];
    const int tid = threadIdx.x;
    const int lane = tid & 63, wave = tid >> 6;
    const int wm = wave >> 1, wn = wave & 1;
    const int lr = lane & 15, lq = lane >> 4;
    const int mBase = blockIdx.y * 128, nBase = blockIdx.x * 128;

    f32x4 acc[4][4];
    #pragma unroll
    for (int i = 0; i < 4; ++i)
        #pragma unroll
        for (int j = 0; j < 4; ++j) acc[i][j] = (f32x4){0.f, 0.f, 0.f, 0.f};

    for (int k0 = 0; k0 < K; k0 += 32) {
        __syncthreads();
        #pragma unroll
        for (int i = 0; i < 2; ++i) {
            int off = i * 4096 + tid * 16;
            int row = off >> 6, col = off & 63;
            *(uint4*)((char*)As + row * 80 + col) =
                *(const uint4*)((const char*)A + ((size_t)(mBase + row) * K + k0) * 2 + col);
            *(uint4*)((char*)Bs + row * 80 + col) =
                *(const uint4*)((const char*)B + ((size_t)(nBase + row) * K + k0) * 2 + col);
        }
        __syncthreads();
        bf16x8 af[4], bfr[4];
        #pragma unroll
        for (int mi = 0; mi < 4; ++mi) af[mi] = *(const bf16x8*)&As[wm * 64 + mi * 16 + lr][lq * 8];
        #pragma unroll
        for (int ni = 0; ni < 4; ++ni) bfr[ni] = *(const bf16x8*)&Bs[wn * 64 + ni * 16 + lr][lq * 8];
        #pragma unroll
        for (int mi = 0; mi < 4; ++mi)
            #pragma unroll
            for (int ni = 0; ni < 4; ++ni)
                acc[mi][ni] = __builtin_amdgcn_mfma_f32_16x16x32_bf16(af[mi], bfr[ni], acc[mi][ni], 0, 0, 0);
    }
    #pragma unroll
    for (int mi = 0; mi < 4; ++mi)
        #pragma unroll
        for (int ni = 0; ni < 4; ++ni)
            #pragma unroll
            for (int r = 0; r < 4; ++r) {
                int m = mBase + wm * 64 + mi * 16 + lq * 4 + r;
                int n = nBase + wn * 64 + ni * 16 + lr;
                C[(size_t)m * N + n] = f2bf(acc[mi][ni][r]);
            }
}

// ---------------- flash attention, split-S, static-max softmax ----------------
// Q,K: [B*S, 512] bf16 row-major. Vt: [512, B*S] bf16 (row stride 16384).
// Grid (32, 8, 2). Static max M=8 in log2 domain (scores*log2e/sqrt(D) is
// O(1), fp32 exp2 has huge headroom) -> no max/sum shuffles, no alpha rescale.
// Writes unnormalized partial O (bf16) + per-row l.
__global__ __launch_bounds__(256, 2)
void attn_kernel(const ushort* __restrict__ Qg, const ushort* __restrict__ Kg,
                 const ushort* __restrict__ Vtg, const int* __restrict__ maskg,
                 ushort* __restrict__ Pog, float* __restrict__ Mlg)
{
    const int S = 2048, D = 512;
    const float SL2E = 0.0637587160f;  // (1/sqrt(512)) * log2(e)

    __shared__ ushort Ks[32][520];   // 32 keys x 512 d (+8 pad)   33280 B
    __shared__ ushort Vs[512][40];   // 512 d   x 32 keys (+8 pad) 40960 B
    __shared__ ushort Ps[4][16][40]; // per-wave P 16x32 (+8 pad)   5120 B

    const int b = blockIdx.y, qt = blockIdx.x, half = blockIdx.z;
    const int tid = threadIdx.x, lane = tid & 63, wave = tid >> 6;
    const int lr = lane & 15, lq = lane >> 4;

    const ushort* Qp = Qg + ((size_t)b * S + qt * 64 + wave * 16 + lr) * D;
    bf16x8 qf[16];
    #pragma unroll
    for (int c = 0; c < 16; ++c) qf[c] = *(const bf16x8*)(Qp + c * 32 + lq * 8);

    f32x4 o[32];
    #pragma unroll
    for (int i = 0; i < 32; ++i) o[i] = (f32x4){0.f, 0.f, 0.f, 0.f};
    float l_i[4] = {0.f, 0.f, 0.f, 0.f};

    const char* Khalf = (const char*)(Kg + (size_t)b * S * D) + (size_t)half * 1024 * 1024;
    const char* Vhalf = (const char*)Vtg + (size_t)b * 4096 + (size_t)half * 2048;
    const int* mrow = maskg + b * S + half * 1024;

    for (int kt = 0; kt < 32; ++kt) {
        const int key0 = kt * 32;
        __syncthreads();   // all waves done reading Ks (QK) and Vs (PV) of prev tile
        {   // K tile via async global->LDS DMA: one 1024B row per instruction
            const char* gK = Khalf + (size_t)key0 * 1024;
            #pragma unroll
            for (int i = 0; i < 8; ++i) {
                int row = wave * 8 + i;
                async_copy16(&Ks[row][0], gK + (size_t)row * 1024 + lane * 16);
            }
        }
        // mask bits for this tile (issue early, used after QK)
        const bool msk0 = mrow[key0 + lr] != 0;
        const bool msk1 = mrow[key0 + 16 + lr] != 0;
        __syncthreads();   // drains K DMA (vmcnt) -> Ks valid
        // V prefetch into regs; consumed after QK+softmax (latency hidden)
        uint4 vreg[8];
        {
            const char* gV = Vhalf + (size_t)key0 * 2;
            #pragma unroll
            for (int i = 0; i < 8; ++i) {
                int off = i * 4096 + tid * 16;
                int row = off >> 6, col = off & 63;
                vreg[i] = *(const uint4*)(gV + (size_t)row * 32768 + col);
            }
        }
        // S = Q Ktile^T
        f32x4 sf0 = (f32x4){0.f,0.f,0.f,0.f}, sf1 = (f32x4){0.f,0.f,0.f,0.f};
        #pragma unroll
        for (int ks = 0; ks < 16; ++ks) {
            bf16x8 kf0 = *(const bf16x8*)&Ks[lr][ks * 32 + lq * 8];
            bf16x8 kf1 = *(const bf16x8*)&Ks[16 + lr][ks * 32 + lq * 8];
            sf0 = __builtin_amdgcn_mfma_f32_16x16x32_bf16(qf[ks], kf0, sf0, 0, 0, 0);
            sf1 = __builtin_amdgcn_mfma_f32_16x16x32_bf16(qf[ks], kf1, sf1, 0, 0, 0);
        }
        // static-max softmax: p = exp2(score*SL2E - 8); l accumulates lane-locally
        #pragma unroll
        for (int r = 0; r < 4; ++r) {
            float p0 = msk0 ? 0.f : exp2f(fmaf(sf0[r], SL2E, -8.f));
            float p1 = msk1 ? 0.f : exp2f(fmaf(sf1[r], SL2E, -8.f));
            l_i[r] += p0 + p1;
            Ps[wave][lq * 4 + r][lr]      = f2bf(p0);
            Ps[wave][lq * 4 + r][16 + lr] = f2bf(p1);
        }
        bf16x8 pf = *(const bf16x8*)&Ps[wave][lr][lq * 8];  // wave-private round-trip
        // V regs -> LDS (vmcnt wait here; loads had the whole QK phase to land)
        #pragma unroll
        for (int i = 0; i < 8; ++i) {
            int off = i * 4096 + tid * 16;
            int row = off >> 6, col = off & 63;
            *(uint4*)((char*)Vs + row * 80 + col) = vreg[i];
        }
        __syncthreads();
        // O += P @ Vt-tile (all 512 d)
        #pragma unroll
        for (int db = 0; db < 32; ++db) {
            bf16x8 vf = *(const bf16x8*)&Vs[db * 16 + lr][lq * 8];
            o[db] = __builtin_amdgcn_mfma_f32_16x16x32_bf16(pf, vf, o[db], 0, 0, 0);
        }
    }
    // final cross-lane l reduction (once per kernel instead of per tile)
    #pragma unroll
    for (int r = 0; r < 4; ++r)
        #pragma unroll
        for (int off = 1; off < 16; off <<= 1)
            l_i[r] += __shfl_xor(l_i[r], off, 16);
    // write unnormalized partial O (bf16) + l per row
    const size_t growbase = (size_t)half * 16384 + (size_t)b * S + qt * 64 + wave * 16;
    ushort* Pop = Pog + (growbase + lq * 4) * D;
    #pragma unroll
    for (int db = 0; db < 32; ++db)
        #pragma unroll
        for (int r = 0; r < 4; ++r)
            Pop[(size_t)r * D + db * 16 + lr] = f2bf(o[db][r]);
    if (lr == 0) {
        #pragma unroll
        for (int r = 0; r < 4; ++r)
            Mlg[growbase + lq * 4 + r] = l_i[r];
    }
}

// ---------------- combine the two key-halves (shared static max) -------------
__global__ __launch_bounds__(256)
void combine_kernel(const ushort* __restrict__ Po, const float* __restrict__ Ml,
                    float* __restrict__ out)
{
    int i = (blockIdx.x * 256 + threadIdx.x) * 4;   // element index into 16384x512
    int row = i >> 9;
    float l = Ml[row] + Ml[16384 + row];
    float s = l > 0.f ? 1.f / l : 0.f;
    ushort4 p1 = *(const ushort4*)(Po + i);
    ushort4 p2 = *(const ushort4*)(Po + 8388608 + i);
    float4 o;
    o.x = (bf2f(p1.x) + bf2f(p2.x)) * s;
    o.y = (bf2f(p1.y) + bf2f(p2.y)) * s;
    o.z = (bf2f(p1.z) + bf2f(p2.z)) * s;
    o.w = (bf2f(p1.w) + bf2f(p2.w)) * s;
    *(float4*)(out + i) = o;
}

extern "C" void kernel_launch(void* const* d_in, const int* in_sizes, int n_in,
                              void* d_out, int out_size, void* d_ws, size_t ws_size,
                              hipStream_t stream) {
    const float* x  = (const float*)d_in[0];
    // d_in[1] = bias: additive scalar on all logits -> softmax shift-invariant -> no-op
    const int* mask = (const int*)d_in[2];
    const float* Wq = (const float*)d_in[3];
    const float* Wk = (const float*)d_in[4];
    const float* Wv = (const float*)d_in[5];
    float* out = (float*)d_out;

    // Workspace (ushort units). Region [0, 16777216) is time-shared:
    //   phase 1 (cvt+gemm): xb (8388608) + wq/wk/wv (3x262144)
    //   phase 2 (attn+combine): Po (2x8388608 bf16 partial O)
    ushort* ws  = (ushort*)d_ws;
    ushort* xb  = ws;
    ushort* wqb = ws + 8388608;
    ushort* wkb = wqb + 262144;
    ushort* wvb = wkb + 262144;
    ushort* Pob = ws;                 // overlaps xb+w (dead after gemms)
    ushort* Qb  = ws + 16777216;
    ushort* Kb  = Qb + 8388608;
    ushort* Vtb = Kb + 8388608;
    float* Mlb = (float*)(Vtb + 8388608);  // 32768 floats

    cvt_f32_bf16<<<8192, 256, 0, stream>>>(x, xb, 8388608);
    cvt_f32_bf16<<<256, 256, 0, stream>>>(Wq, wqb, 262144);
    cvt_f32_bf16<<<256, 256, 0, stream>>>(Wk, wkb, 262144);
    cvt_f32_bf16<<<256, 256, 0, stream>>>(Wv, wvb, 262144);
    gemm_bt<<<dim3(4, 128), 256, 0, stream>>>(xb, wqb, Qb, 16384, 512, 512);
    gemm_bt<<<dim3(4, 128), 256, 0, stream>>>(xb, wkb, Kb, 16384, 512, 512);
    gemm_bt<<<dim3(128, 4), 256, 0, stream>>>(wvb, xb, Vtb, 512, 16384, 512);
    attn_kernel<<<dim3(32, 8, 2), 256, 0, stream>>>(Qb, Kb, Vtb, mask, Pob, Mlb);
    combine_kernel<<<8192, 256, 0, stream>>>(Pob, Mlb, out);
}

// Round 4
// 298.183 us; speedup vs baseline: 1.6045x; 1.0368x over previous
//
#include <hip/hip_runtime.h>

typedef short bf16x8 __attribute__((ext_vector_type(8)));
typedef float f32x4 __attribute__((ext_vector_type(4)));
typedef float f32x16 __attribute__((ext_vector_type(16)));

__device__ __forceinline__ ushort f2bf(float f) {
    union { float f; unsigned u; } v; v.f = f;
    unsigned r = (v.u + 0x7fffu + ((v.u >> 16) & 1u)) >> 16;
    return (ushort)r;
}
__device__ __forceinline__ float bf2f(ushort u) {
    union { unsigned u; float f; } v; v.u = ((unsigned)u) << 16;
    return v.f;
}
__device__ __forceinline__ void async_copy16(void* lds, const void* g) {
    __builtin_amdgcn_global_load_lds(
        (const __attribute__((address_space(1))) unsigned*)g,
        (__attribute__((address_space(3))) unsigned*)lds, 16, 0, 0);
}

// ---------------- fp32 -> bf16 conversion ----------------
__global__ __launch_bounds__(256)
void cvt_f32_bf16(const float* __restrict__ src, ushort* __restrict__ dst, int n) {
    int i = (blockIdx.x * 256 + threadIdx.x) * 4;
    if (i >= n) return;
    float4 v = *(const float4*)(src + i);
    ushort4 o;
    o.x = f2bf(v.x); o.y = f2bf(v.y); o.z = f2bf(v.z); o.w = f2bf(v.w);
    *(ushort4*)(dst + i) = o;
}

// fused weight conversion: Wq|Wk|Wv (3 x 262144) -> contiguous bf16 stack
__global__ __launch_bounds__(256)
void cvt_w(const float* __restrict__ a, const float* __restrict__ b,
           const float* __restrict__ c, ushort* __restrict__ dst) {
    int i = (blockIdx.x * 256 + threadIdx.x) * 4;
    const float* src; int off;
    if (i < 262144)      { src = a; off = i; }
    else if (i < 524288) { src = b; off = i - 262144; }
    else                 { src = c; off = i - 524288; }
    float4 v = *(const float4*)(src + off);
    ushort4 o;
    o.x = f2bf(v.x); o.y = f2bf(v.y); o.z = f2bf(v.z); o.w = f2bf(v.w);
    *(ushort4*)(dst + i) = o;
}

// ---------------- C[m][n] = sum_k A[m][k] * B[n][k], bf16 in/out, fp32 acc ----
__global__ __launch_bounds__(256, 2)
void gemm_bt(const ushort* __restrict__ A, const ushort* __restrict__ B,
             ushort* __restrict__ C, int M, int N, int K)
{
    __shared__ ushort As[128][40];
    __shared__ ushort Bs[128][40];
    const int tid = threadIdx.x;
    const int lane = tid & 63, wave = tid >> 6;
    const int wm = wave >> 1, wn = wave & 1;
    const int lr = lane & 15, lq = lane >> 4;
    const int mBase = blockIdx.y * 128, nBase = blockIdx.x * 128;

    f32x4 acc[4][4];
    #pragma unroll
    for (int i = 0; i < 4; ++i)
        #pragma unroll
        for (int j = 0; j < 4; ++j) acc[i][j] = (f32x4){0.f, 0.f, 0.f, 0.f};

    for (int k0 = 0; k0 < K; k0 += 32) {
        __syncthreads();
        #pragma unroll
        for (int i = 0; i < 2; ++i) {
            int off = i * 4096 + tid * 16;
            int row = off >> 6, col = off & 63;
            *(uint4*)((char*)As + row * 80 + col) =
                *(const uint4*)((const char*)A + ((size_t)(mBase + row) * K + k0) * 2 + col);
            *(uint4*)((char*)Bs + row * 80 + col) =
                *(const uint4*)((const char*)B + ((size_t)(nBase + row) * K + k0) * 2 + col);
        }
        __syncthreads();
        bf16x8 af[4], bfr[4];
        #pragma unroll
        for (int mi = 0; mi < 4; ++mi) af[mi] = *(const bf16x8*)&As[wm * 64 + mi * 16 + lr][lq * 8];
        #pragma unroll
        for (int ni = 0; ni < 4; ++ni) bfr[ni] = *(const bf16x8*)&Bs[wn * 64 + ni * 16 + lr][lq * 8];
        #pragma unroll
        for (int mi = 0; mi < 4; ++mi)
            #pragma unroll
            for (int ni = 0; ni < 4; ++ni)
                acc[mi][ni] = __builtin_amdgcn_mfma_f32_16x16x32_bf16(af[mi], bfr[ni], acc[mi][ni], 0, 0, 0);
    }
    #pragma unroll
    for (int mi = 0; mi < 4; ++mi)
        #pragma unroll
        for (int ni = 0; ni < 4; ++ni)
            #pragma unroll
            for (int r = 0; r < 4; ++r) {
                int m = mBase + wm * 64 + mi * 16 + lq * 4 + r;
                int n = nBase + wn * 64 + ni * 16 + lr;
                C[(size_t)m * N + n] = f2bf(acc[mi][ni][r]);
            }
}

// ---------------- flash attention, split-S, static-max, pair-split PV -------
// QK: [B*S][1024] bf16 (col 0..511 = Q, 512..1023 = K). Vt: [512][B*S] bf16.
// Grid (32, 8, 2). Wave w: QK+softmax for rows [16w,16w+16). PV by wave
// pairs p=w>>1, s=w&1: pair shares P (32x32 in LDS), each member computes
// O for the pair's 32 rows over d in [256s, 256s+256) via mfma 32x32x16.
// V LDS traffic per wave-iter: 16 KB (vs 32 KB unsplit).
__global__ __launch_bounds__(256, 2)
void attn_kernel(const ushort* __restrict__ QKg, const ushort* __restrict__ Vtg,
                 const int* __restrict__ maskg,
                 ushort* __restrict__ Pog, float* __restrict__ Mlg)
{
    const int S = 2048;
    const float SL2E = 0.0637587160f;  // (1/sqrt(512)) * log2(e)

    __shared__ ushort Ks[32][548];   // 32 keys x 512 d; stride 1096B=274dw==18 mod 32
    __shared__ ushort Vs[512][36];   // 512 d x 32 keys; stride 72B=18dw==18 mod 32
    __shared__ ushort Ps[2][32][36]; // per-pair P 32 rows x 32 keys

    const int b = blockIdx.y, qt = blockIdx.x, half = blockIdx.z;
    const int tid = threadIdx.x, lane = tid & 63, wave = tid >> 6;
    const int lr = lane & 15, lq = lane >> 4;
    const int p = wave >> 1, s = wave & 1;
    const int l32 = lane & 31, lh = lane >> 5;

    // resident Q fragments (QK stride 1024, Q at col 0)
    const ushort* Qp = QKg + ((size_t)b * S + qt * 64 + wave * 16 + lr) * 1024;
    bf16x8 qf[16];
    #pragma unroll
    for (int c = 0; c < 16; ++c) qf[c] = *(const bf16x8*)(Qp + c * 32 + lq * 8);

    f32x16 o[8];
    #pragma unroll
    for (int i = 0; i < 8; ++i)
        #pragma unroll
        for (int r = 0; r < 16; ++r) o[i][r] = 0.f;
    float l_i[4] = {0.f, 0.f, 0.f, 0.f};

    const ushort* Khalf = QKg + ((size_t)b * S + half * 1024) * 1024 + 512;
    const char* Vhalf = (const char*)Vtg + ((size_t)b * 2048 + half * 1024) * 2;
    const int* mrow = maskg + b * S + half * 1024;

    for (int kt = 0; kt < 32; ++kt) {
        const int key0 = kt * 32;
        __syncthreads();   // prev tile fully consumed (Ks/Vs/Ps)
        {   // K tile via async global->LDS DMA: one 1024B row per instruction
            #pragma unroll
            for (int i = 0; i < 8; ++i) {
                int row = wave * 8 + i;
                async_copy16(&Ks[row][0],
                             (const char*)(Khalf + (size_t)(key0 + row) * 1024) + lane * 16);
            }
        }
        const bool msk0 = mrow[key0 + lr] != 0;
        const bool msk1 = mrow[key0 + 16 + lr] != 0;
        __syncthreads();   // drains K DMA -> Ks valid
        // V prefetch into regs; consumed after QK+softmax (latency hidden)
        uint4 vreg[8];
        {
            const char* gV = Vhalf + (size_t)key0 * 2;
            #pragma unroll
            for (int i = 0; i < 8; ++i) {
                int off = i * 4096 + tid * 16;
                int row = off >> 6, col = off & 63;
                vreg[i] = *(const uint4*)(gV + (size_t)row * 32768 + col);
            }
        }
        // S = Q Ktile^T (16x16x32; B-frag from Ks rows)
        f32x4 sf0 = (f32x4){0.f,0.f,0.f,0.f}, sf1 = (f32x4){0.f,0.f,0.f,0.f};
        #pragma unroll
        for (int ks = 0; ks < 16; ++ks) {
            bf16x8 kf0 = *(const bf16x8*)&Ks[lr][ks * 32 + lq * 8];
            bf16x8 kf1 = *(const bf16x8*)&Ks[16 + lr][ks * 32 + lq * 8];
            sf0 = __builtin_amdgcn_mfma_f32_16x16x32_bf16(qf[ks], kf0, sf0, 0, 0, 0);
            sf1 = __builtin_amdgcn_mfma_f32_16x16x32_bf16(qf[ks], kf1, sf1, 0, 0, 0);
        }
        // static-max softmax: p = exp2(score*SL2E - 8); l lane-local
        #pragma unroll
        for (int r = 0; r < 4; ++r) {
            float p0 = msk0 ? 0.f : exp2f(fmaf(sf0[r], SL2E, -8.f));
            float p1 = msk1 ? 0.f : exp2f(fmaf(sf1[r], SL2E, -8.f));
            l_i[r] += p0 + p1;
            Ps[p][16 * s + lq * 4 + r][lr]      = f2bf(p0);
            Ps[p][16 * s + lq * 4 + r][16 + lr] = f2bf(p1);
        }
        // V regs -> LDS
        #pragma unroll
        for (int i = 0; i < 8; ++i) {
            int off = i * 4096 + tid * 16;
            int row = off >> 6, col = off & 63;
            *(uint4*)((char*)Vs + row * 72 + col) = vreg[i];
        }
        __syncthreads();   // P (cross-wave within pair) + V visible
        // O += P(32x32) @ V(32xd256) via mfma 32x32x16, d-range by s
        bf16x8 pA0 = *(const bf16x8*)&Ps[p][l32][lh * 8];
        bf16x8 pA1 = *(const bf16x8*)&Ps[p][l32][16 + lh * 8];
        #pragma unroll
        for (int dt = 0; dt < 8; ++dt) {
            int d = s * 256 + dt * 32 + l32;
            bf16x8 v0 = *(const bf16x8*)&Vs[d][lh * 8];
            bf16x8 v1 = *(const bf16x8*)&Vs[d][16 + lh * 8];
            o[dt] = __builtin_amdgcn_mfma_f32_32x32x16_bf16(pA0, v0, o[dt], 0, 0, 0);
            o[dt] = __builtin_amdgcn_mfma_f32_32x32x16_bf16(pA1, v1, o[dt], 0, 0, 0);
        }
    }
    // final cross-lane l reduction (QK-wave owns rows 16w..16w+16)
    #pragma unroll
    for (int r = 0; r < 4; ++r)
        #pragma unroll
        for (int off = 1; off < 16; off <<= 1)
            l_i[r] += __shfl_xor(l_i[r], off, 16);
    const size_t growbase = (size_t)half * 16384 + (size_t)b * S + qt * 64;
    if (lr == 0) {
        #pragma unroll
        for (int r = 0; r < 4; ++r)
            Mlg[growbase + wave * 16 + lq * 4 + r] = l_i[r];
    }
    // write unnormalized partial O: pair rows [32p,32p+32), cols [256s,256s+256)
    // 32x32 C-layout: col = lane&31, row = (r&3) + 8*(r>>2) + 4*(lane>>5)
    ushort* Pop = Pog + (growbase + p * 32) * 512;
    #pragma unroll
    for (int dt = 0; dt < 8; ++dt) {
        int ocol = s * 256 + dt * 32 + l32;
        #pragma unroll
        for (int r = 0; r < 16; ++r) {
            int orow = (r & 3) + 8 * (r >> 2) + 4 * lh;
            Pop[(size_t)orow * 512 + ocol] = f2bf(o[dt][r]);
        }
    }
}

// ---------------- combine the two key-halves (shared static max) -------------
__global__ __launch_bounds__(256)
void combine_kernel(const ushort* __restrict__ Po, const float* __restrict__ Ml,
                    float* __restrict__ out)
{
    int i = (blockIdx.x * 256 + threadIdx.x) * 4;
    int row = i >> 9;
    float l = Ml[row] + Ml[16384 + row];
    float s = l > 0.f ? 1.f / l : 0.f;
    ushort4 p1 = *(const ushort4*)(Po + i);
    ushort4 p2 = *(const ushort4*)(Po + 8388608 + i);
    float4 o;
    o.x = (bf2f(p1.x) + bf2f(p2.x)) * s;
    o.y = (bf2f(p1.y) + bf2f(p2.y)) * s;
    o.z = (bf2f(p1.z) + bf2f(p2.z)) * s;
    o.w = (bf2f(p1.w) + bf2f(p2.w)) * s;
    *(float4*)(out + i) = o;
}

extern "C" void kernel_launch(void* const* d_in, const int* in_sizes, int n_in,
                              void* d_out, int out_size, void* d_ws, size_t ws_size,
                              hipStream_t stream) {
    const float* x  = (const float*)d_in[0];
    // d_in[1] = bias: additive scalar on all logits -> softmax shift-invariant -> no-op
    const int* mask = (const int*)d_in[2];
    const float* Wq = (const float*)d_in[3];
    const float* Wk = (const float*)d_in[4];
    const float* Wv = (const float*)d_in[5];
    float* out = (float*)d_out;

    // Workspace (ushort units). Region [0, 16777216) time-shared:
    //   phase 1: xb (8388608) + W-stack wq|wk|wv (786432)
    //   phase 2: Po (2 x 8388608 bf16 partial O)
    ushort* ws  = (ushort*)d_ws;
    ushort* xb  = ws;
    ushort* wst = ws + 8388608;            // Wq|Wk|Wv stacked (1536 x 512)
    ushort* Pob = ws;
    ushort* QKb = ws + 16777216;           // 16384 x 1024  ([Q|K] per row)
    ushort* Vtb = ws + 33554432;           // 512 x 16384   (V transposed)
    float*  Mlb = (float*)(ws + 41943040); // 32768 floats

    cvt_f32_bf16<<<8192, 256, 0, stream>>>(x, xb, 8388608);
    cvt_w<<<768, 256, 0, stream>>>(Wq, Wk, Wv, wst);
    // [Q|K] = x [Wq;Wk]^T  (M=16384, N=1024, K=512)
    gemm_bt<<<dim3(8, 128), 256, 0, stream>>>(xb, wst, QKb, 16384, 1024, 512);
    // Vt = Wv x^T  (M=512, N=16384, K=512)
    gemm_bt<<<dim3(128, 4), 256, 0, stream>>>(wst + 524288, xb, Vtb, 512, 16384, 512);
    attn_kernel<<<dim3(32, 8, 2), 256, 0, stream>>>(QKb, Vtb, mask, Pob, Mlb);
    combine_kernel<<<8192, 256, 0, stream>>>(Pob, Mlb, out);
}